// Round 6
// baseline (29259.549 us; speedup 1.0000x reference)
//
#include <hip/hip_runtime.h>

// Seq2Seq LSTM (H=1024, B=64, T=512), persistent-grid, f16 MFMA, f32 state.
// Round-6 coherence protocol:
//  - producers store h via sc0sc1 (write-through to LLC; vmcnt-drained
//    before barrier flag) — no dirty L2 lines ever.
//  - consumers read h via NORMAL CACHED loads, after a per-step
//    fence(acquire, agent) = buffer_inv (invalidate-only, no writeback).
//    Each XCD's L2 then refetches fresh h from LLC once and serves its
//    32 WGs locally (round-5's all-LLC path was the bottleneck: 64 MB/step
//    of fine-grained LLC requests, 90% idle).
//  - encoder: 1 barrier/step; decoder: +barrier-B only when mask[t]==0.
//  - h ping-pong in MFMA-A-fragment-swizzled order (full-line wave loads);
//    layer-1 h0 fragments register-carried into layer-0 of t+1.

#define HD 1024
#define BB 64
#define TT 512
#define NWG 256
#define NTHR 256

typedef _Float16 f16x8 __attribute__((ext_vector_type(8)));
typedef float f32x4 __attribute__((ext_vector_type(4)));
typedef unsigned long long u64;

struct KP {
  const float* seq;
  const int* mask;
  const float* Wih0;
  const float* Whh0;
  const float* b0;
  const float* Wih1;
  const float* Whh1;
  const float* b1;
  const float* fcW;
  const float* fcb;
  _Float16* h0buf;   // [2][4][32][64][8] swizzled f16
  _Float16* h1buf;
  float* c0buf;
  float* c1buf;
  float* predpart;   // [2][16][B]
  int* flags;
  float* out;
};

__device__ __forceinline__ float sigm(float x) { return 1.0f / (1.0f + expf(-x)); }

__device__ __forceinline__ u64 cload_u64(const void* p) {
  return __hip_atomic_load((const u64*)p, __ATOMIC_RELAXED, __HIP_MEMORY_SCOPE_SYSTEM);
}
__device__ __forceinline__ void cstore_u64(void* p, u64 v) {
  __hip_atomic_store((u64*)p, v, __ATOMIC_RELAXED, __HIP_MEMORY_SCOPE_SYSTEM);
}
__device__ __forceinline__ float cload_f32(const float* p) {
  return __hip_atomic_load(p, __ATOMIC_RELAXED, __HIP_MEMORY_SCOPE_SYSTEM);
}
__device__ __forceinline__ void cstore_f32(float* p, float v) {
  __hip_atomic_store(p, v, __ATOMIC_RELAXED, __HIP_MEMORY_SCOPE_SYSTEM);
}
__device__ __forceinline__ f16x8 cload_a(const _Float16* p) {
  union { u64 q[2]; f16x8 v; } c;
  c.q[0] = cload_u64(p);
  c.q[1] = cload_u64(p + 4);
  return c.v;
}

__device__ __forceinline__ void gbar(int* flags, int epoch) {
  asm volatile("s_waitcnt vmcnt(0)" ::: "memory");
  __syncthreads();
  if (threadIdx.x == 0) {
    __hip_atomic_store(&flags[blockIdx.x], epoch, __ATOMIC_RELAXED, __HIP_MEMORY_SCOPE_SYSTEM);
  }
  if (threadIdx.x < 64) {
#pragma unroll
    for (int i = 0; i < NWG / 64; ++i) {
      int idx = (int)threadIdx.x + i * 64;
      while (__hip_atomic_load(&flags[idx], __ATOMIC_RELAXED, __HIP_MEMORY_SCOPE_AGENT) < epoch)
        __builtin_amdgcn_s_sleep(1);
    }
  }
  asm volatile("" ::: "memory");
  __syncthreads();
}

__global__ void init_kernel(_Float16* h0, _Float16* h1, float* predpart, int* fe, int* fd) {
  int i = blockIdx.x * blockDim.x + threadIdx.x;
  int stride = gridDim.x * blockDim.x;
  for (int j = i; j < 2 * BB * HD; j += stride) {
    h0[j] = (_Float16)0.0f;
    h1[j] = (_Float16)0.0f;
  }
  for (int j = i; j < 2 * 16 * BB; j += stride) predpart[j] = 0.0f;
  if (i < NWG) {
    fe[i] = 0;
    fd[i] = 0;
  }
}

template <int IS_DEC>
__global__ __launch_bounds__(NTHR, 1) void seq_kernel(KP p) {
  __shared__ _Float16 ldsW[2][32][64][8];  // 64 KB: layer-1 W fragments

  const int tid = threadIdx.x;
  const int wg = blockIdx.x;
  const int wave = tid >> 6;
  const int lane = tid & 63;
  const int n = lane & 15;
  const int q = lane >> 4;
  const int gidx = n & 3;
  const int u = n >> 2;
  const int unitG = wg * 4 + u;
  const int rowG = gidx * HD + unitG;
  const int koff = q * 8;

  const int kc0 = wg >> 3;
  const int q0 = (wg >> 1) & 3;
  const int j8b = (wg & 1) * 4;
  const int stoff = (((wave * 32 + kc0) << 6) + (q0 << 4) + n) * 8 + j8b;
  const int Lb = ((n >> 2) << 4) | (n & 3);
  const int aoff = ((wave * 32) << 6 | lane) * 8;

  // ---- stage layer-1 weights into LDS (fragment-swizzled) ----
  for (int g = tid; g < 4096; g += NTHR) {
    int mat = g >> 11;
    int gg = g & 2047;
    int kc = gg >> 6;
    int lv = gg & 63;
    int nn = lv & 15, qq = lv >> 4;
    int rG = (nn & 3) * HD + (wg * 4 + (nn >> 2));
    const float* src = (mat == 0 ? p.Wih1 : p.Whh1) + rG * HD + kc * 32 + qq * 8;
#pragma unroll
    for (int j = 0; j < 8; ++j) ldsW[mat][kc][lv][j] = (_Float16)src[j];
  }

  // ---- layer-0 hidden weights as register B-fragments ----
  f16x8 wf0[32];
#pragma unroll
  for (int kc = 0; kc < 32; ++kc) {
    const float* src = p.Whh0 + rowG * HD + kc * 32 + koff;
    f16x8 v;
#pragma unroll
    for (int j = 0; j < 8; ++j) v[j] = (_Float16)src[j];
    wf0[kc] = v;
  }

  const float bias0 = p.b0[rowG];
  const float bias1 = p.b1[rowG];
  const float wih0 = p.Wih0[rowG];
  const float fcw = p.fcW[unitG];
  const float fcb = p.fcb[0];

  float c0r[4], c1r[4];
#pragma unroll
  for (int r = 0; r < 4; ++r) {
    if (IS_DEC) {
      int b = wave * 16 + q * 4 + r;
      c0r[r] = p.c0buf[b * HD + unitG];
      c1r[r] = p.c1buf[b * HD + unitG];
    } else {
      c0r[r] = 0.0f;
      c1r[r] = 0.0f;
    }
  }
  __syncthreads();

  // ---- bootstrap haf = h0(prev) via coherent loads (avoids stale L2 at
  //      kernel entry) ----
  f16x8 haf[32];
  {
    const _Float16* hb = p.h0buf + BB * HD + aoff;
#pragma unroll
    for (int kc = 0; kc < 32; ++kc) haf[kc] = cload_a(hb + kc * 512);
  }

  int epoch = 1;
  for (int t = 0; t < TT; ++t) {
    const int wp = t & 1;
    _Float16* h0w = p.h0buf + wp * (BB * HD);
    _Float16* h1w = p.h1buf + wp * (BB * HD);
    const _Float16* h1r = p.h1buf + (1 - wp) * (BB * HD);

    // ================= layer 0 (register-carried h0, zero global loads) ===
    f32x4 acca = {0.0f, 0.0f, 0.0f, 0.0f};
    f32x4 accb = {0.0f, 0.0f, 0.0f, 0.0f};
#pragma unroll
    for (int kc = 0; kc < 32; kc += 2) {
      acca = __builtin_amdgcn_mfma_f32_16x16x32_f16(haf[kc], wf0[kc], acca, 0, 0, 0);
      accb = __builtin_amdgcn_mfma_f32_16x16x32_f16(haf[kc + 1], wf0[kc + 1], accb, 0, 0, 0);
    }
    f32x4 acc = acca + accb;

    float xv[4];
    if (!IS_DEC) {
#pragma unroll
      for (int r = 0; r < 4; ++r) {
        int b = wave * 16 + q * 4 + r;
        xv[r] = p.seq[b * TT + t];
      }
    } else {
      if (t == 0) {
#pragma unroll
        for (int r = 0; r < 4; ++r) xv[r] = 0.0f;
      } else if (p.mask[t - 1] != 0) {
#pragma unroll
        for (int r = 0; r < 4; ++r) {
          int b = wave * 16 + q * 4 + r;
          xv[r] = p.seq[b * TT + (t - 1)];
        }
      } else {
        const float* pp = p.predpart + ((t - 1) & 1) * (16 * BB);
#pragma unroll
        for (int r = 0; r < 4; ++r) {
          int b = wave * 16 + q * 4 + r;
          float s = 0.0f;
#pragma unroll
          for (int j3 = 0; j3 < 4; ++j3) s += cload_f32(pp + (gidx * 4 + j3) * BB + b);
          s += __shfl_xor(s, 1);
          s += __shfl_xor(s, 2);
          xv[r] = s + fcb;
        }
      }
    }

    float hn0[4];
#pragma unroll
    for (int r = 0; r < 4; ++r) {
      float v = acc[r] + bias0 + xv[r] * wih0;
      float v1 = __shfl_xor(v, 1);
      float v2 = __shfl_xor(v, 2);
      float v3 = __shfl_xor(v, 3);
      float gi = (gidx == 0) ? v : (gidx == 1) ? v1 : (gidx == 2) ? v2 : v3;
      float gf = (gidx == 1) ? v : (gidx == 0) ? v1 : (gidx == 3) ? v2 : v3;
      float gg = (gidx == 2) ? v : (gidx == 3) ? v1 : (gidx == 0) ? v2 : v3;
      float go = (gidx == 3) ? v : (gidx == 2) ? v1 : (gidx == 1) ? v2 : v3;
      float cn = sigm(gf) * c0r[r] + sigm(gi) * tanhf(gg);
      hn0[r] = sigm(go) * tanhf(cn);
      c0r[r] = cn;
    }
    {
      int hb0 = (int)(unsigned)__builtin_bit_cast(unsigned short, (_Float16)hn0[0]);
      int hb1 = (int)(unsigned)__builtin_bit_cast(unsigned short, (_Float16)hn0[1]);
      int hb2 = (int)(unsigned)__builtin_bit_cast(unsigned short, (_Float16)hn0[2]);
      int hb3 = (int)(unsigned)__builtin_bit_cast(unsigned short, (_Float16)hn0[3]);
      int iv = (gidx == 0) ? hb0 : (gidx == 1) ? hb1 : (gidx == 2) ? hb2 : hb3;
      int w0 = __shfl(iv, Lb);
      int w1 = __shfl(iv, Lb + 4);
      int w2 = __shfl(iv, Lb + 8);
      int w3 = __shfl(iv, Lb + 12);
      u64 lo = (unsigned)(w0 & 0xFFFF) | ((unsigned)(w1 & 0xFFFF) << 16);
      u64 hi = (unsigned)(w2 & 0xFFFF) | ((unsigned)(w3 & 0xFFFF) << 16);
      u64 pk = lo | (hi << 32);
      if (q == q0) cstore_u64(h0w + stoff, pk);
    }
    gbar(p.flags, epoch++);  // barrier A
    // invalidate L1+L2 (no writeback: nothing dirty) -> cached h loads below
    // refetch fresh lines from LLC, once per XCD, then hit L2.
    __builtin_amdgcn_fence(__ATOMIC_ACQUIRE, "agent");

    // ================= layer 1 =================
    if (IS_DEC && wg == 0 && t > 0 && tid < BB) {
      const float* pp = p.predpart + ((t - 1) & 1) * (16 * BB);
      float s = fcb;
#pragma unroll
      for (int j2 = 0; j2 < 16; ++j2) s += cload_f32(pp + j2 * BB + tid);
      p.out[tid * TT + (t - 1)] = s;
      asm volatile("" ::: "memory");
      float* pz = p.predpart + ((t - 1) & 1) * (16 * BB);
#pragma unroll
      for (int j2 = 0; j2 < 16; ++j2) cstore_f32(pz + j2 * BB + tid, 0.0f);
    }

    f32x4 acc2a = {0.0f, 0.0f, 0.0f, 0.0f};
    f32x4 acc2b = {0.0f, 0.0f, 0.0f, 0.0f};
    {
      const _Float16* Ax = h0w + aoff;
      const _Float16* Ah = h1r + aoff;
#pragma unroll
      for (int kc = 0; kc < 32; kc += 2) {
        f16x8 a0 = *(const f16x8*)(Ax + kc * 512);          // cached load
        haf[kc] = a0;
        acc2a = __builtin_amdgcn_mfma_f32_16x16x32_f16(a0, *(const f16x8*)(&ldsW[0][kc][lane][0]), acc2a, 0, 0, 0);
        f16x8 a1 = *(const f16x8*)(Ah + kc * 512);
        acc2a = __builtin_amdgcn_mfma_f32_16x16x32_f16(a1, *(const f16x8*)(&ldsW[1][kc][lane][0]), acc2a, 0, 0, 0);
        f16x8 a0b = *(const f16x8*)(Ax + (kc + 1) * 512);
        haf[kc + 1] = a0b;
        acc2b = __builtin_amdgcn_mfma_f32_16x16x32_f16(a0b, *(const f16x8*)(&ldsW[0][kc + 1][lane][0]), acc2b, 0, 0, 0);
        f16x8 a1b = *(const f16x8*)(Ah + (kc + 1) * 512);
        acc2b = __builtin_amdgcn_mfma_f32_16x16x32_f16(a1b, *(const f16x8*)(&ldsW[1][kc + 1][lane][0]), acc2b, 0, 0, 0);
      }
    }
    f32x4 acc2 = acc2a + acc2b;

    float hn1[4];
#pragma unroll
    for (int r = 0; r < 4; ++r) {
      float v = acc2[r] + bias1;
      float v1 = __shfl_xor(v, 1);
      float v2 = __shfl_xor(v, 2);
      float v3 = __shfl_xor(v, 3);
      float gi = (gidx == 0) ? v : (gidx == 1) ? v1 : (gidx == 2) ? v2 : v3;
      float gf = (gidx == 1) ? v : (gidx == 0) ? v1 : (gidx == 3) ? v2 : v3;
      float gg = (gidx == 2) ? v : (gidx == 3) ? v1 : (gidx == 0) ? v2 : v3;
      float go = (gidx == 3) ? v : (gidx == 2) ? v1 : (gidx == 1) ? v2 : v3;
      float cn = sigm(gf) * c1r[r] + sigm(gi) * tanhf(gg);
      float hn = sigm(go) * tanhf(cn);
      hn1[r] = hn;
      c1r[r] = cn;
      if (IS_DEC) {
        float pl = (gidx == 0) ? hn * fcw : 0.0f;
        pl += __shfl_xor(pl, 1);
        pl += __shfl_xor(pl, 2);
        pl += __shfl_xor(pl, 4);
        pl += __shfl_xor(pl, 8);
        if (n == 0) {
          int b = wave * 16 + q * 4 + r;
          atomicAdd(p.predpart + (t & 1) * (16 * BB) + (wg >> 4) * BB + b, pl);
        }
      }
    }
    {
      int hb0 = (int)(unsigned)__builtin_bit_cast(unsigned short, (_Float16)hn1[0]);
      int hb1 = (int)(unsigned)__builtin_bit_cast(unsigned short, (_Float16)hn1[1]);
      int hb2 = (int)(unsigned)__builtin_bit_cast(unsigned short, (_Float16)hn1[2]);
      int hb3 = (int)(unsigned)__builtin_bit_cast(unsigned short, (_Float16)hn1[3]);
      int iv = (gidx == 0) ? hb0 : (gidx == 1) ? hb1 : (gidx == 2) ? hb2 : hb3;
      int w0 = __shfl(iv, Lb);
      int w1 = __shfl(iv, Lb + 4);
      int w2 = __shfl(iv, Lb + 8);
      int w3 = __shfl(iv, Lb + 12);
      u64 lo = (unsigned)(w0 & 0xFFFF) | ((unsigned)(w1 & 0xFFFF) << 16);
      u64 hi = (unsigned)(w2 & 0xFFFF) | ((unsigned)(w3 & 0xFFFF) << 16);
      u64 pk = lo | (hi << 32);
      if (q == q0) cstore_u64(h1w + stoff, pk);
    }

    if (IS_DEC) {
      if (t == TT - 1 || p.mask[t] == 0) gbar(p.flags, epoch++);
    }
  }

  if (!IS_DEC) {
    if (gidx == 0) {
#pragma unroll
      for (int r = 0; r < 4; ++r) {
        int b = wave * 16 + q * 4 + r;
        p.c0buf[b * HD + unitG] = c0r[r];
        p.c1buf[b * HD + unitG] = c1r[r];
      }
    }
  } else {
    if (wg == 0 && tid < BB) {
      const float* pp = p.predpart + ((TT - 1) & 1) * (16 * BB);
      float s = fcb;
#pragma unroll
      for (int j2 = 0; j2 < 16; ++j2) s += cload_f32(pp + j2 * BB + tid);
      p.out[tid * TT + (TT - 1)] = s;
    }
  }
}

extern "C" void kernel_launch(void* const* d_in, const int* in_sizes, int n_in,
                              void* d_out, int out_size, void* d_ws, size_t ws_size,
                              hipStream_t stream) {
  (void)in_sizes; (void)n_in; (void)out_size; (void)ws_size;
  const float* prev = (const float*)d_in[0];
  const float* nxt = (const float*)d_in[1];
  const int* mask = (const int*)d_in[2];
  const float* eWih0 = (const float*)d_in[3];
  const float* eWhh0 = (const float*)d_in[4];
  const float* eb0 = (const float*)d_in[5];
  const float* eWih1 = (const float*)d_in[6];
  const float* eWhh1 = (const float*)d_in[7];
  const float* eb1 = (const float*)d_in[8];
  const float* dWih0 = (const float*)d_in[9];
  const float* dWhh0 = (const float*)d_in[10];
  const float* db0 = (const float*)d_in[11];
  const float* dWih1 = (const float*)d_in[12];
  const float* dWhh1 = (const float*)d_in[13];
  const float* db1 = (const float*)d_in[14];
  const float* fcW = (const float*)d_in[15];
  const float* fcb = (const float*)d_in[16];

  char* w = (char*)d_ws;
  _Float16* h0buf = (_Float16*)w; w += 2 * BB * HD * 2;
  _Float16* h1buf = (_Float16*)w; w += 2 * BB * HD * 2;
  float* c0buf = (float*)w; w += BB * HD * 4;
  float* c1buf = (float*)w; w += BB * HD * 4;
  float* predpart = (float*)w; w += 2 * 16 * BB * 4;
  int* flagsE = (int*)w; w += NWG * 4;
  int* flagsD = (int*)w; w += NWG * 4;

  init_kernel<<<dim3(128), dim3(256), 0, stream>>>(h0buf, h1buf, predpart, flagsE, flagsD);

  KP pe;
  pe.seq = prev; pe.mask = mask;
  pe.Wih0 = eWih0; pe.Whh0 = eWhh0; pe.b0 = eb0;
  pe.Wih1 = eWih1; pe.Whh1 = eWhh1; pe.b1 = eb1;
  pe.fcW = fcW; pe.fcb = fcb;
  pe.h0buf = h0buf; pe.h1buf = h1buf;
  pe.c0buf = c0buf; pe.c1buf = c1buf;
  pe.predpart = predpart; pe.flags = flagsE;
  pe.out = (float*)d_out;
  seq_kernel<0><<<dim3(NWG), dim3(NTHR), 0, stream>>>(pe);

  KP pd = pe;
  pd.seq = nxt;
  pd.Wih0 = dWih0; pd.Whh0 = dWhh0; pd.b0 = db0;
  pd.Wih1 = dWih1; pd.Whh1 = dWhh1; pd.b1 = db1;
  pd.flags = flagsD;
  seq_kernel<1><<<dim3(NWG), dim3(NTHR), 0, stream>>>(pd);
}

// Round 8
// 14724.826 us; speedup vs baseline: 1.9871x; 1.9871x over previous
//
#include <hip/hip_runtime.h>

// Seq2Seq LSTM (H=1024, B=64, T=512), persistent-grid, f16 MFMA, f32 state.
// Round-8 = round-5 protocol (pure sc0sc1 coherent h traffic, no cache
// fences) + BULK-ISSUED compiler-tracked coherent loads:
//   issue haf[0..31] (Ax) then ahf[0..31] (Ah) as ordinary relaxed-atomic
//   loads, THEN run both MFMA groups. Compiler inserts fine-grained
//   s_waitcnt vmcnt(N) before first use; all 128 dwordx2 requests pipeline
//   at full depth instead of round-5's load->mfma->load serialization.
//   (Round-7's inline-asm variant was unsafe: asm-hidden VMEM breaks the
//   compiler's waitcnt ledger -> crash. This version is fully tracked.)
// haf register-carry: Ax fragments reused as layer-0 input of step t+1.
// Encoder: 1 grid barrier/step; decoder adds barrier-B only when mask[t]==0.

#define HD 1024
#define BB 64
#define TT 512
#define NWG 256
#define NTHR 256

typedef _Float16 f16x8 __attribute__((ext_vector_type(8)));
typedef float f32x4 __attribute__((ext_vector_type(4)));
typedef unsigned long long u64;

struct KP {
  const float* seq;
  const int* mask;
  const float* Wih0;
  const float* Whh0;
  const float* b0;
  const float* Wih1;
  const float* Whh1;
  const float* b1;
  const float* fcW;
  const float* fcb;
  _Float16* h0buf;   // [2][4][32][64][8] swizzled f16
  _Float16* h1buf;
  float* c0buf;
  float* c1buf;
  float* predpart;   // [2][16][B]
  int* flags;
  float* out;
};

__device__ __forceinline__ float sigm(float x) { return 1.0f / (1.0f + expf(-x)); }

__device__ __forceinline__ u64 cload_u64(const void* p) {
  return __hip_atomic_load((const u64*)p, __ATOMIC_RELAXED, __HIP_MEMORY_SCOPE_SYSTEM);
}
__device__ __forceinline__ void cstore_u64(void* p, u64 v) {
  __hip_atomic_store((u64*)p, v, __ATOMIC_RELAXED, __HIP_MEMORY_SCOPE_SYSTEM);
}
__device__ __forceinline__ float cload_f32(const float* p) {
  return __hip_atomic_load(p, __ATOMIC_RELAXED, __HIP_MEMORY_SCOPE_SYSTEM);
}
__device__ __forceinline__ void cstore_f32(float* p, float v) {
  __hip_atomic_store(p, v, __ATOMIC_RELAXED, __HIP_MEMORY_SCOPE_SYSTEM);
}
__device__ __forceinline__ f16x8 cload_a(const _Float16* p) {
  union { u64 q[2]; f16x8 v; } c;
  c.q[0] = cload_u64(p);
  c.q[1] = cload_u64(p + 4);
  return c.v;
}

__device__ __forceinline__ void gbar(int* flags, int epoch) {
  asm volatile("s_waitcnt vmcnt(0)" ::: "memory");
  __syncthreads();
  if (threadIdx.x == 0) {
    __hip_atomic_store(&flags[blockIdx.x], epoch, __ATOMIC_RELAXED, __HIP_MEMORY_SCOPE_SYSTEM);
  }
  if (threadIdx.x < 64) {
#pragma unroll
    for (int i = 0; i < NWG / 64; ++i) {
      int idx = (int)threadIdx.x + i * 64;
      while (__hip_atomic_load(&flags[idx], __ATOMIC_RELAXED, __HIP_MEMORY_SCOPE_AGENT) < epoch)
        __builtin_amdgcn_s_sleep(1);
    }
  }
  asm volatile("" ::: "memory");
  __syncthreads();
}

__global__ void init_kernel(_Float16* h0, _Float16* h1, float* predpart, int* fe, int* fd) {
  int i = blockIdx.x * blockDim.x + threadIdx.x;
  int stride = gridDim.x * blockDim.x;
  for (int j = i; j < 2 * BB * HD; j += stride) {
    h0[j] = (_Float16)0.0f;
    h1[j] = (_Float16)0.0f;
  }
  for (int j = i; j < 2 * 16 * BB; j += stride) predpart[j] = 0.0f;
  if (i < NWG) {
    fe[i] = 0;
    fd[i] = 0;
  }
}

template <int IS_DEC>
__global__ __launch_bounds__(NTHR, 1) void seq_kernel(KP p) {
  __shared__ _Float16 ldsW[2][32][64][8];  // 64 KB: layer-1 W fragments

  const int tid = threadIdx.x;
  const int wg = blockIdx.x;
  const int wave = tid >> 6;
  const int lane = tid & 63;
  const int n = lane & 15;
  const int q = lane >> 4;
  const int gidx = n & 3;
  const int u = n >> 2;
  const int unitG = wg * 4 + u;
  const int rowG = gidx * HD + unitG;
  const int koff = q * 8;

  const int kc0 = wg >> 3;
  const int q0 = (wg >> 1) & 3;
  const int j8b = (wg & 1) * 4;
  const int stoff = (((wave * 32 + kc0) << 6) + (q0 << 4) + n) * 8 + j8b;
  const int Lb = ((n >> 2) << 4) | (n & 3);
  const int aoff = ((wave * 32) << 6 | lane) * 8;

  // ---- stage layer-1 weights into LDS (fragment-swizzled) ----
  for (int g = tid; g < 4096; g += NTHR) {
    int mat = g >> 11;
    int gg = g & 2047;
    int kc = gg >> 6;
    int lv = gg & 63;
    int nn = lv & 15, qq = lv >> 4;
    int rG = (nn & 3) * HD + (wg * 4 + (nn >> 2));
    const float* src = (mat == 0 ? p.Wih1 : p.Whh1) + rG * HD + kc * 32 + qq * 8;
#pragma unroll
    for (int j = 0; j < 8; ++j) ldsW[mat][kc][lv][j] = (_Float16)src[j];
  }

  // ---- layer-0 hidden weights as register B-fragments ----
  f16x8 wf0[32];
#pragma unroll
  for (int kc = 0; kc < 32; ++kc) {
    const float* src = p.Whh0 + rowG * HD + kc * 32 + koff;
    f16x8 v;
#pragma unroll
    for (int j = 0; j < 8; ++j) v[j] = (_Float16)src[j];
    wf0[kc] = v;
  }

  const float bias0 = p.b0[rowG];
  const float bias1 = p.b1[rowG];
  const float wih0 = p.Wih0[rowG];
  const float fcw = p.fcW[unitG];
  const float fcb = p.fcb[0];

  float c0r[4], c1r[4];
#pragma unroll
  for (int r = 0; r < 4; ++r) {
    if (IS_DEC) {
      int b = wave * 16 + q * 4 + r;
      c0r[r] = p.c0buf[b * HD + unitG];
      c1r[r] = p.c1buf[b * HD + unitG];
    } else {
      c0r[r] = 0.0f;
      c1r[r] = 0.0f;
    }
  }
  __syncthreads();

  // ---- bootstrap haf = h0(prev) ----
  f16x8 haf[32];
  {
    const _Float16* hb = p.h0buf + BB * HD + aoff;
#pragma unroll
    for (int kc = 0; kc < 32; ++kc) haf[kc] = cload_a(hb + kc * 512);
  }

  int epoch = 1;
  for (int t = 0; t < TT; ++t) {
    const int wp = t & 1;
    _Float16* h0w = p.h0buf + wp * (BB * HD);
    _Float16* h1w = p.h1buf + wp * (BB * HD);
    const _Float16* h1r = p.h1buf + (1 - wp) * (BB * HD);

    // ================= layer 0 (register-carried h0, zero global loads) ===
    f32x4 acca = {0.0f, 0.0f, 0.0f, 0.0f};
    f32x4 accb = {0.0f, 0.0f, 0.0f, 0.0f};
#pragma unroll
    for (int kc = 0; kc < 32; kc += 2) {
      acca = __builtin_amdgcn_mfma_f32_16x16x32_f16(haf[kc], wf0[kc], acca, 0, 0, 0);
      accb = __builtin_amdgcn_mfma_f32_16x16x32_f16(haf[kc + 1], wf0[kc + 1], accb, 0, 0, 0);
    }
    f32x4 acc = acca + accb;

    float xv[4];
    if (!IS_DEC) {
#pragma unroll
      for (int r = 0; r < 4; ++r) {
        int b = wave * 16 + q * 4 + r;
        xv[r] = p.seq[b * TT + t];
      }
    } else {
      if (t == 0) {
#pragma unroll
        for (int r = 0; r < 4; ++r) xv[r] = 0.0f;
      } else if (p.mask[t - 1] != 0) {
#pragma unroll
        for (int r = 0; r < 4; ++r) {
          int b = wave * 16 + q * 4 + r;
          xv[r] = p.seq[b * TT + (t - 1)];
        }
      } else {
        const float* pp = p.predpart + ((t - 1) & 1) * (16 * BB);
#pragma unroll
        for (int r = 0; r < 4; ++r) {
          int b = wave * 16 + q * 4 + r;
          float s = 0.0f;
#pragma unroll
          for (int j3 = 0; j3 < 4; ++j3) s += cload_f32(pp + (gidx * 4 + j3) * BB + b);
          s += __shfl_xor(s, 1);
          s += __shfl_xor(s, 2);
          xv[r] = s + fcb;
        }
      }
    }

    float hn0[4];
#pragma unroll
    for (int r = 0; r < 4; ++r) {
      float v = acc[r] + bias0 + xv[r] * wih0;
      float v1 = __shfl_xor(v, 1);
      float v2 = __shfl_xor(v, 2);
      float v3 = __shfl_xor(v, 3);
      float gi = (gidx == 0) ? v : (gidx == 1) ? v1 : (gidx == 2) ? v2 : v3;
      float gf = (gidx == 1) ? v : (gidx == 0) ? v1 : (gidx == 3) ? v2 : v3;
      float gg = (gidx == 2) ? v : (gidx == 3) ? v1 : (gidx == 0) ? v2 : v3;
      float go = (gidx == 3) ? v : (gidx == 2) ? v1 : (gidx == 1) ? v2 : v3;
      float cn = sigm(gf) * c0r[r] + sigm(gi) * tanhf(gg);
      hn0[r] = sigm(go) * tanhf(cn);
      c0r[r] = cn;
    }
    {
      int hb0 = (int)(unsigned)__builtin_bit_cast(unsigned short, (_Float16)hn0[0]);
      int hb1 = (int)(unsigned)__builtin_bit_cast(unsigned short, (_Float16)hn0[1]);
      int hb2 = (int)(unsigned)__builtin_bit_cast(unsigned short, (_Float16)hn0[2]);
      int hb3 = (int)(unsigned)__builtin_bit_cast(unsigned short, (_Float16)hn0[3]);
      int iv = (gidx == 0) ? hb0 : (gidx == 1) ? hb1 : (gidx == 2) ? hb2 : hb3;
      int w0 = __shfl(iv, Lb);
      int w1 = __shfl(iv, Lb + 4);
      int w2 = __shfl(iv, Lb + 8);
      int w3 = __shfl(iv, Lb + 12);
      u64 lo = (unsigned)(w0 & 0xFFFF) | ((unsigned)(w1 & 0xFFFF) << 16);
      u64 hi = (unsigned)(w2 & 0xFFFF) | ((unsigned)(w3 & 0xFFFF) << 16);
      u64 pk = lo | (hi << 32);
      if (q == q0) cstore_u64(h0w + stoff, pk);
    }
    gbar(p.flags, epoch++);  // barrier A

    // ================= layer 1 =================
    // decoder bookkeeping first (small, completes inside this block)
    if (IS_DEC && wg == 0 && t > 0 && tid < BB) {
      const float* pp = p.predpart + ((t - 1) & 1) * (16 * BB);
      float s = fcb;
#pragma unroll
      for (int j2 = 0; j2 < 16; ++j2) s += cload_f32(pp + j2 * BB + tid);
      p.out[tid * TT + (t - 1)] = s;
      asm volatile("" ::: "memory");
      float* pz = p.predpart + ((t - 1) & 1) * (16 * BB);
#pragma unroll
      for (int j2 = 0; j2 < 16; ++j2) cstore_f32(pz + j2 * BB + tid, 0.0f);
    }

    // bulk-issue ALL coherent fragment loads (compiler-tracked), then MFMA.
    f16x8 ahf[32];
    {
      const _Float16* Ax = h0w + aoff;
      const _Float16* Ah = h1r + aoff;
#pragma unroll
      for (int kc = 0; kc < 32; ++kc) haf[kc] = cload_a(Ax + kc * 512);
#pragma unroll
      for (int kc = 0; kc < 32; ++kc) ahf[kc] = cload_a(Ah + kc * 512);
      asm volatile("" ::: "memory");  // pin loads above the MFMA phase
    }
    f32x4 acc2a = {0.0f, 0.0f, 0.0f, 0.0f};
    f32x4 acc2b = {0.0f, 0.0f, 0.0f, 0.0f};
#pragma unroll
    for (int kc = 0; kc < 32; kc += 2) {
      acc2a = __builtin_amdgcn_mfma_f32_16x16x32_f16(haf[kc], *(const f16x8*)(&ldsW[0][kc][lane][0]), acc2a, 0, 0, 0);
      acc2b = __builtin_amdgcn_mfma_f32_16x16x32_f16(haf[kc + 1], *(const f16x8*)(&ldsW[0][kc + 1][lane][0]), acc2b, 0, 0, 0);
    }
#pragma unroll
    for (int kc = 0; kc < 32; kc += 2) {
      acc2a = __builtin_amdgcn_mfma_f32_16x16x32_f16(ahf[kc], *(const f16x8*)(&ldsW[1][kc][lane][0]), acc2a, 0, 0, 0);
      acc2b = __builtin_amdgcn_mfma_f32_16x16x32_f16(ahf[kc + 1], *(const f16x8*)(&ldsW[1][kc + 1][lane][0]), acc2b, 0, 0, 0);
    }
    f32x4 acc2 = acc2a + acc2b;

    float hn1[4];
#pragma unroll
    for (int r = 0; r < 4; ++r) {
      float v = acc2[r] + bias1;
      float v1 = __shfl_xor(v, 1);
      float v2 = __shfl_xor(v, 2);
      float v3 = __shfl_xor(v, 3);
      float gi = (gidx == 0) ? v : (gidx == 1) ? v1 : (gidx == 2) ? v2 : v3;
      float gf = (gidx == 1) ? v : (gidx == 0) ? v1 : (gidx == 3) ? v2 : v3;
      float gg = (gidx == 2) ? v : (gidx == 3) ? v1 : (gidx == 0) ? v2 : v3;
      float go = (gidx == 3) ? v : (gidx == 2) ? v1 : (gidx == 1) ? v2 : v3;
      float cn = sigm(gf) * c1r[r] + sigm(gi) * tanhf(gg);
      float hn = sigm(go) * tanhf(cn);
      hn1[r] = hn;
      c1r[r] = cn;
      if (IS_DEC) {
        float pl = (gidx == 0) ? hn * fcw : 0.0f;
        pl += __shfl_xor(pl, 1);
        pl += __shfl_xor(pl, 2);
        pl += __shfl_xor(pl, 4);
        pl += __shfl_xor(pl, 8);
        if (n == 0) {
          int b = wave * 16 + q * 4 + r;
          atomicAdd(p.predpart + (t & 1) * (16 * BB) + (wg >> 4) * BB + b, pl);
        }
      }
    }
    {
      int hb0 = (int)(unsigned)__builtin_bit_cast(unsigned short, (_Float16)hn1[0]);
      int hb1 = (int)(unsigned)__builtin_bit_cast(unsigned short, (_Float16)hn1[1]);
      int hb2 = (int)(unsigned)__builtin_bit_cast(unsigned short, (_Float16)hn1[2]);
      int hb3 = (int)(unsigned)__builtin_bit_cast(unsigned short, (_Float16)hn1[3]);
      int iv = (gidx == 0) ? hb0 : (gidx == 1) ? hb1 : (gidx == 2) ? hb2 : hb3;
      int w0 = __shfl(iv, Lb);
      int w1 = __shfl(iv, Lb + 4);
      int w2 = __shfl(iv, Lb + 8);
      int w3 = __shfl(iv, Lb + 12);
      u64 lo = (unsigned)(w0 & 0xFFFF) | ((unsigned)(w1 & 0xFFFF) << 16);
      u64 hi = (unsigned)(w2 & 0xFFFF) | ((unsigned)(w3 & 0xFFFF) << 16);
      u64 pk = lo | (hi << 32);
      if (q == q0) cstore_u64(h1w + stoff, pk);
    }

    if (IS_DEC) {
      if (t == TT - 1 || p.mask[t] == 0) gbar(p.flags, epoch++);
    }
  }

  if (!IS_DEC) {
    if (gidx == 0) {
#pragma unroll
      for (int r = 0; r < 4; ++r) {
        int b = wave * 16 + q * 4 + r;
        p.c0buf[b * HD + unitG] = c0r[r];
        p.c1buf[b * HD + unitG] = c1r[r];
      }
    }
  } else {
    if (wg == 0 && tid < BB) {
      const float* pp = p.predpart + ((TT - 1) & 1) * (16 * BB);
      float s = fcb;
#pragma unroll
      for (int j2 = 0; j2 < 16; ++j2) s += cload_f32(pp + j2 * BB + tid);
      p.out[tid * TT + (TT - 1)] = s;
    }
  }
}

extern "C" void kernel_launch(void* const* d_in, const int* in_sizes, int n_in,
                              void* d_out, int out_size, void* d_ws, size_t ws_size,
                              hipStream_t stream) {
  (void)in_sizes; (void)n_in; (void)out_size; (void)ws_size;
  const float* prev = (const float*)d_in[0];
  const float* nxt = (const float*)d_in[1];
  const int* mask = (const int*)d_in[2];
  const float* eWih0 = (const float*)d_in[3];
  const float* eWhh0 = (const float*)d_in[4];
  const float* eb0 = (const float*)d_in[5];
  const float* eWih1 = (const float*)d_in[6];
  const float* eWhh1 = (const float*)d_in[7];
  const float* eb1 = (const float*)d_in[8];
  const float* dWih0 = (const float*)d_in[9];
  const float* dWhh0 = (const float*)d_in[10];
  const float* db0 = (const float*)d_in[11];
  const float* dWih1 = (const float*)d_in[12];
  const float* dWhh1 = (const float*)d_in[13];
  const float* db1 = (const float*)d_in[14];
  const float* fcW = (const float*)d_in[15];
  const float* fcb = (const float*)d_in[16];

  char* w = (char*)d_ws;
  _Float16* h0buf = (_Float16*)w; w += 2 * BB * HD * 2;
  _Float16* h1buf = (_Float16*)w; w += 2 * BB * HD * 2;
  float* c0buf = (float*)w; w += BB * HD * 4;
  float* c1buf = (float*)w; w += BB * HD * 4;
  float* predpart = (float*)w; w += 2 * 16 * BB * 4;
  int* flagsE = (int*)w; w += NWG * 4;
  int* flagsD = (int*)w; w += NWG * 4;

  init_kernel<<<dim3(128), dim3(256), 0, stream>>>(h0buf, h1buf, predpart, flagsE, flagsD);

  KP pe;
  pe.seq = prev; pe.mask = mask;
  pe.Wih0 = eWih0; pe.Whh0 = eWhh0; pe.b0 = eb0;
  pe.Wih1 = eWih1; pe.Whh1 = eWhh1; pe.b1 = eb1;
  pe.fcW = fcW; pe.fcb = fcb;
  pe.h0buf = h0buf; pe.h1buf = h1buf;
  pe.c0buf = c0buf; pe.c1buf = c1buf;
  pe.predpart = predpart; pe.flags = flagsE;
  pe.out = (float*)d_out;
  seq_kernel<0><<<dim3(NWG), dim3(NTHR), 0, stream>>>(pe);

  KP pd = pe;
  pd.seq = nxt;
  pd.Wih0 = dWih0; pd.Whh0 = dWhh0; pd.b0 = db0;
  pd.Wih1 = dWih1; pd.Whh1 = dWhh1; pd.b1 = db1;
  pd.flags = flagsD;
  seq_kernel<1><<<dim3(NWG), dim3(NTHR), 0, stream>>>(pd);
}

// Round 9
// 11890.266 us; speedup vs baseline: 2.4608x; 1.2384x over previous
//
#include <hip/hip_runtime.h>

// Seq2Seq LSTM (H=1024, B=64, T=512), persistent-grid, f16 MFMA, f32 state.
// Round-9 = round-8 (bulk compiler-tracked sc0sc1 coherent loads, register-
// carried h0 fragments, swizzled h layout, 1 barrier/step encoder) with the
// barrier rebuilt as MASTER-BROADCAST:
//   - WG 255 (master): each of its 256 threads polls ONE flag; after all
//     arrive, thread 0 publishes a single `go` epoch word (flags[NWG]).
//   - every other WG: thread 0 stores its flag then polls ONLY `go`.
// Round-8's all-poll-all barrier generated ~64 LLC line-requests per wave
// per poll round (~21 req/cyc grid-wide) — as much traffic as the data
// phase itself, congesting the LLC exactly while data loads drained.

#define HD 1024
#define BB 64
#define TT 512
#define NWG 256
#define NTHR 256

typedef _Float16 f16x8 __attribute__((ext_vector_type(8)));
typedef float f32x4 __attribute__((ext_vector_type(4)));
typedef unsigned long long u64;

struct KP {
  const float* seq;
  const int* mask;
  const float* Wih0;
  const float* Whh0;
  const float* b0;
  const float* Wih1;
  const float* Whh1;
  const float* b1;
  const float* fcW;
  const float* fcb;
  _Float16* h0buf;   // [2][4][32][64][8] swizzled f16
  _Float16* h1buf;
  float* c0buf;
  float* c1buf;
  float* predpart;   // [2][16][B]
  int* flags;        // [NWG+1]; flags[NWG] = go word
  float* out;
};

__device__ __forceinline__ float sigm(float x) { return 1.0f / (1.0f + expf(-x)); }

__device__ __forceinline__ u64 cload_u64(const void* p) {
  return __hip_atomic_load((const u64*)p, __ATOMIC_RELAXED, __HIP_MEMORY_SCOPE_SYSTEM);
}
__device__ __forceinline__ void cstore_u64(void* p, u64 v) {
  __hip_atomic_store((u64*)p, v, __ATOMIC_RELAXED, __HIP_MEMORY_SCOPE_SYSTEM);
}
__device__ __forceinline__ float cload_f32(const float* p) {
  return __hip_atomic_load(p, __ATOMIC_RELAXED, __HIP_MEMORY_SCOPE_SYSTEM);
}
__device__ __forceinline__ void cstore_f32(float* p, float v) {
  __hip_atomic_store(p, v, __ATOMIC_RELAXED, __HIP_MEMORY_SCOPE_SYSTEM);
}
__device__ __forceinline__ int cload_i32(const int* p) {
  return __hip_atomic_load(p, __ATOMIC_RELAXED, __HIP_MEMORY_SCOPE_SYSTEM);
}
__device__ __forceinline__ void cstore_i32(int* p, int v) {
  __hip_atomic_store(p, v, __ATOMIC_RELAXED, __HIP_MEMORY_SCOPE_SYSTEM);
}
__device__ __forceinline__ f16x8 cload_a(const _Float16* p) {
  union { u64 q[2]; f16x8 v; } c;
  c.q[0] = cload_u64(p);
  c.q[1] = cload_u64(p + 4);
  return c.v;
}

// Master-broadcast grid barrier. All cross-WG data moves via sc0sc1 (LLC);
// per-wave vmcnt(0) drain before flag/go ensures store visibility.
__device__ __forceinline__ void gbar(int* flags, int epoch) {
  asm volatile("s_waitcnt vmcnt(0)" ::: "memory");
  __syncthreads();
  int* go = flags + NWG;
  if (blockIdx.x == NWG - 1) {
    // master: thread tid owns flags[tid] (NTHR == NWG); own WG implied.
    if ((int)threadIdx.x < NWG - 1) {
      while (cload_i32(&flags[threadIdx.x]) < epoch)
        __builtin_amdgcn_s_sleep(1);
    }
    __syncthreads();
    if (threadIdx.x == 0) cstore_i32(go, epoch);
  } else {
    if (threadIdx.x == 0) {
      cstore_i32(&flags[blockIdx.x], epoch);
      while (cload_i32(go) < epoch)
        __builtin_amdgcn_s_sleep(1);
    }
    __syncthreads();
  }
  asm volatile("" ::: "memory");
}

__global__ void init_kernel(_Float16* h0, _Float16* h1, float* predpart, int* fe, int* fd) {
  int i = blockIdx.x * blockDim.x + threadIdx.x;
  int stride = gridDim.x * blockDim.x;
  for (int j = i; j < 2 * BB * HD; j += stride) {
    h0[j] = (_Float16)0.0f;
    h1[j] = (_Float16)0.0f;
  }
  for (int j = i; j < 2 * 16 * BB; j += stride) predpart[j] = 0.0f;
  if (i < NWG + 1) {
    fe[i] = 0;
    fd[i] = 0;
  }
}

template <int IS_DEC>
__global__ __launch_bounds__(NTHR, 1) void seq_kernel(KP p) {
  __shared__ _Float16 ldsW[2][32][64][8];  // 64 KB: layer-1 W fragments

  const int tid = threadIdx.x;
  const int wg = blockIdx.x;
  const int wave = tid >> 6;
  const int lane = tid & 63;
  const int n = lane & 15;
  const int q = lane >> 4;
  const int gidx = n & 3;
  const int u = n >> 2;
  const int unitG = wg * 4 + u;
  const int rowG = gidx * HD + unitG;
  const int koff = q * 8;

  const int kc0 = wg >> 3;
  const int q0 = (wg >> 1) & 3;
  const int j8b = (wg & 1) * 4;
  const int stoff = (((wave * 32 + kc0) << 6) + (q0 << 4) + n) * 8 + j8b;
  const int Lb = ((n >> 2) << 4) | (n & 3);
  const int aoff = ((wave * 32) << 6 | lane) * 8;

  // ---- stage layer-1 weights into LDS (fragment-swizzled) ----
  for (int g = tid; g < 4096; g += NTHR) {
    int mat = g >> 11;
    int gg = g & 2047;
    int kc = gg >> 6;
    int lv = gg & 63;
    int nn = lv & 15, qq = lv >> 4;
    int rG = (nn & 3) * HD + (wg * 4 + (nn >> 2));
    const float* src = (mat == 0 ? p.Wih1 : p.Whh1) + rG * HD + kc * 32 + qq * 8;
#pragma unroll
    for (int j = 0; j < 8; ++j) ldsW[mat][kc][lv][j] = (_Float16)src[j];
  }

  // ---- layer-0 hidden weights as register B-fragments ----
  f16x8 wf0[32];
#pragma unroll
  for (int kc = 0; kc < 32; ++kc) {
    const float* src = p.Whh0 + rowG * HD + kc * 32 + koff;
    f16x8 v;
#pragma unroll
    for (int j = 0; j < 8; ++j) v[j] = (_Float16)src[j];
    wf0[kc] = v;
  }

  const float bias0 = p.b0[rowG];
  const float bias1 = p.b1[rowG];
  const float wih0 = p.Wih0[rowG];
  const float fcw = p.fcW[unitG];
  const float fcb = p.fcb[0];

  float c0r[4], c1r[4];
#pragma unroll
  for (int r = 0; r < 4; ++r) {
    if (IS_DEC) {
      int b = wave * 16 + q * 4 + r;
      c0r[r] = p.c0buf[b * HD + unitG];
      c1r[r] = p.c1buf[b * HD + unitG];
    } else {
      c0r[r] = 0.0f;
      c1r[r] = 0.0f;
    }
  }
  __syncthreads();

  // ---- bootstrap haf = h0(prev) ----
  f16x8 haf[32];
  {
    const _Float16* hb = p.h0buf + BB * HD + aoff;
#pragma unroll
    for (int kc = 0; kc < 32; ++kc) haf[kc] = cload_a(hb + kc * 512);
  }

  int epoch = 1;
  for (int t = 0; t < TT; ++t) {
    const int wp = t & 1;
    _Float16* h0w = p.h0buf + wp * (BB * HD);
    _Float16* h1w = p.h1buf + wp * (BB * HD);
    const _Float16* h1r = p.h1buf + (1 - wp) * (BB * HD);

    // ================= layer 0 (register-carried h0, zero global loads) ===
    f32x4 acca = {0.0f, 0.0f, 0.0f, 0.0f};
    f32x4 accb = {0.0f, 0.0f, 0.0f, 0.0f};
#pragma unroll
    for (int kc = 0; kc < 32; kc += 2) {
      acca = __builtin_amdgcn_mfma_f32_16x16x32_f16(haf[kc], wf0[kc], acca, 0, 0, 0);
      accb = __builtin_amdgcn_mfma_f32_16x16x32_f16(haf[kc + 1], wf0[kc + 1], accb, 0, 0, 0);
    }
    f32x4 acc = acca + accb;

    float xv[4];
    if (!IS_DEC) {
#pragma unroll
      for (int r = 0; r < 4; ++r) {
        int b = wave * 16 + q * 4 + r;
        xv[r] = p.seq[b * TT + t];
      }
    } else {
      if (t == 0) {
#pragma unroll
        for (int r = 0; r < 4; ++r) xv[r] = 0.0f;
      } else if (p.mask[t - 1] != 0) {
#pragma unroll
        for (int r = 0; r < 4; ++r) {
          int b = wave * 16 + q * 4 + r;
          xv[r] = p.seq[b * TT + (t - 1)];
        }
      } else {
        const float* pp = p.predpart + ((t - 1) & 1) * (16 * BB);
#pragma unroll
        for (int r = 0; r < 4; ++r) {
          int b = wave * 16 + q * 4 + r;
          float s = 0.0f;
#pragma unroll
          for (int j3 = 0; j3 < 4; ++j3) s += cload_f32(pp + (gidx * 4 + j3) * BB + b);
          s += __shfl_xor(s, 1);
          s += __shfl_xor(s, 2);
          xv[r] = s + fcb;
        }
      }
    }

    float hn0[4];
#pragma unroll
    for (int r = 0; r < 4; ++r) {
      float v = acc[r] + bias0 + xv[r] * wih0;
      float v1 = __shfl_xor(v, 1);
      float v2 = __shfl_xor(v, 2);
      float v3 = __shfl_xor(v, 3);
      float gi = (gidx == 0) ? v : (gidx == 1) ? v1 : (gidx == 2) ? v2 : v3;
      float gf = (gidx == 1) ? v : (gidx == 0) ? v1 : (gidx == 3) ? v2 : v3;
      float gg = (gidx == 2) ? v : (gidx == 3) ? v1 : (gidx == 0) ? v2 : v3;
      float go = (gidx == 3) ? v : (gidx == 2) ? v1 : (gidx == 1) ? v2 : v3;
      float cn = sigm(gf) * c0r[r] + sigm(gi) * tanhf(gg);
      hn0[r] = sigm(go) * tanhf(cn);
      c0r[r] = cn;
    }
    {
      int hb0 = (int)(unsigned)__builtin_bit_cast(unsigned short, (_Float16)hn0[0]);
      int hb1 = (int)(unsigned)__builtin_bit_cast(unsigned short, (_Float16)hn0[1]);
      int hb2 = (int)(unsigned)__builtin_bit_cast(unsigned short, (_Float16)hn0[2]);
      int hb3 = (int)(unsigned)__builtin_bit_cast(unsigned short, (_Float16)hn0[3]);
      int iv = (gidx == 0) ? hb0 : (gidx == 1) ? hb1 : (gidx == 2) ? hb2 : hb3;
      int w0 = __shfl(iv, Lb);
      int w1 = __shfl(iv, Lb + 4);
      int w2 = __shfl(iv, Lb + 8);
      int w3 = __shfl(iv, Lb + 12);
      u64 lo = (unsigned)(w0 & 0xFFFF) | ((unsigned)(w1 & 0xFFFF) << 16);
      u64 hi = (unsigned)(w2 & 0xFFFF) | ((unsigned)(w3 & 0xFFFF) << 16);
      u64 pk = lo | (hi << 32);
      if (q == q0) cstore_u64(h0w + stoff, pk);
    }
    gbar(p.flags, epoch++);  // barrier A (master-broadcast)

    // ================= layer 1 =================
    // decoder bookkeeping first (small, completes inside this block)
    if (IS_DEC && wg == 0 && t > 0 && tid < BB) {
      const float* pp = p.predpart + ((t - 1) & 1) * (16 * BB);
      float s = fcb;
#pragma unroll
      for (int j2 = 0; j2 < 16; ++j2) s += cload_f32(pp + j2 * BB + tid);
      p.out[tid * TT + (t - 1)] = s;
      asm volatile("" ::: "memory");
      float* pz = p.predpart + ((t - 1) & 1) * (16 * BB);
#pragma unroll
      for (int j2 = 0; j2 < 16; ++j2) cstore_f32(pz + j2 * BB + tid, 0.0f);
    }

    // bulk-issue ALL coherent fragment loads (compiler-tracked), then MFMA.
    f16x8 ahf[32];
    {
      const _Float16* Ax = h0w + aoff;
      const _Float16* Ah = h1r + aoff;
#pragma unroll
      for (int kc = 0; kc < 32; ++kc) haf[kc] = cload_a(Ax + kc * 512);
#pragma unroll
      for (int kc = 0; kc < 32; ++kc) ahf[kc] = cload_a(Ah + kc * 512);
      asm volatile("" ::: "memory");  // pin loads above the MFMA phase
    }
    f32x4 acc2a = {0.0f, 0.0f, 0.0f, 0.0f};
    f32x4 acc2b = {0.0f, 0.0f, 0.0f, 0.0f};
#pragma unroll
    for (int kc = 0; kc < 32; kc += 2) {
      acc2a = __builtin_amdgcn_mfma_f32_16x16x32_f16(haf[kc], *(const f16x8*)(&ldsW[0][kc][lane][0]), acc2a, 0, 0, 0);
      acc2b = __builtin_amdgcn_mfma_f32_16x16x32_f16(haf[kc + 1], *(const f16x8*)(&ldsW[0][kc + 1][lane][0]), acc2b, 0, 0, 0);
    }
#pragma unroll
    for (int kc = 0; kc < 32; kc += 2) {
      acc2a = __builtin_amdgcn_mfma_f32_16x16x32_f16(ahf[kc], *(const f16x8*)(&ldsW[1][kc][lane][0]), acc2a, 0, 0, 0);
      acc2b = __builtin_amdgcn_mfma_f32_16x16x32_f16(ahf[kc + 1], *(const f16x8*)(&ldsW[1][kc + 1][lane][0]), acc2b, 0, 0, 0);
    }
    f32x4 acc2 = acc2a + acc2b;

    float hn1[4];
#pragma unroll
    for (int r = 0; r < 4; ++r) {
      float v = acc2[r] + bias1;
      float v1 = __shfl_xor(v, 1);
      float v2 = __shfl_xor(v, 2);
      float v3 = __shfl_xor(v, 3);
      float gi = (gidx == 0) ? v : (gidx == 1) ? v1 : (gidx == 2) ? v2 : v3;
      float gf = (gidx == 1) ? v : (gidx == 0) ? v1 : (gidx == 3) ? v2 : v3;
      float gg = (gidx == 2) ? v : (gidx == 3) ? v1 : (gidx == 0) ? v2 : v3;
      float go = (gidx == 3) ? v : (gidx == 2) ? v1 : (gidx == 1) ? v2 : v3;
      float cn = sigm(gf) * c1r[r] + sigm(gi) * tanhf(gg);
      float hn = sigm(go) * tanhf(cn);
      hn1[r] = hn;
      c1r[r] = cn;
      if (IS_DEC) {
        float pl = (gidx == 0) ? hn * fcw : 0.0f;
        pl += __shfl_xor(pl, 1);
        pl += __shfl_xor(pl, 2);
        pl += __shfl_xor(pl, 4);
        pl += __shfl_xor(pl, 8);
        if (n == 0) {
          int b = wave * 16 + q * 4 + r;
          atomicAdd(p.predpart + (t & 1) * (16 * BB) + (wg >> 4) * BB + b, pl);
        }
      }
    }
    {
      int hb0 = (int)(unsigned)__builtin_bit_cast(unsigned short, (_Float16)hn1[0]);
      int hb1 = (int)(unsigned)__builtin_bit_cast(unsigned short, (_Float16)hn1[1]);
      int hb2 = (int)(unsigned)__builtin_bit_cast(unsigned short, (_Float16)hn1[2]);
      int hb3 = (int)(unsigned)__builtin_bit_cast(unsigned short, (_Float16)hn1[3]);
      int iv = (gidx == 0) ? hb0 : (gidx == 1) ? hb1 : (gidx == 2) ? hb2 : hb3;
      int w0 = __shfl(iv, Lb);
      int w1 = __shfl(iv, Lb + 4);
      int w2 = __shfl(iv, Lb + 8);
      int w3 = __shfl(iv, Lb + 12);
      u64 lo = (unsigned)(w0 & 0xFFFF) | ((unsigned)(w1 & 0xFFFF) << 16);
      u64 hi = (unsigned)(w2 & 0xFFFF) | ((unsigned)(w3 & 0xFFFF) << 16);
      u64 pk = lo | (hi << 32);
      if (q == q0) cstore_u64(h1w + stoff, pk);
    }

    if (IS_DEC) {
      if (t == TT - 1 || p.mask[t] == 0) gbar(p.flags, epoch++);
    }
  }

  if (!IS_DEC) {
    if (gidx == 0) {
#pragma unroll
      for (int r = 0; r < 4; ++r) {
        int b = wave * 16 + q * 4 + r;
        p.c0buf[b * HD + unitG] = c0r[r];
        p.c1buf[b * HD + unitG] = c1r[r];
      }
    }
  } else {
    if (wg == 0 && tid < BB) {
      const float* pp = p.predpart + ((TT - 1) & 1) * (16 * BB);
      float s = fcb;
#pragma unroll
      for (int j2 = 0; j2 < 16; ++j2) s += cload_f32(pp + j2 * BB + tid);
      p.out[tid * TT + (TT - 1)] = s;
    }
  }
}

extern "C" void kernel_launch(void* const* d_in, const int* in_sizes, int n_in,
                              void* d_out, int out_size, void* d_ws, size_t ws_size,
                              hipStream_t stream) {
  (void)in_sizes; (void)n_in; (void)out_size; (void)ws_size;
  const float* prev = (const float*)d_in[0];
  const float* nxt = (const float*)d_in[1];
  const int* mask = (const int*)d_in[2];
  const float* eWih0 = (const float*)d_in[3];
  const float* eWhh0 = (const float*)d_in[4];
  const float* eb0 = (const float*)d_in[5];
  const float* eWih1 = (const float*)d_in[6];
  const float* eWhh1 = (const float*)d_in[7];
  const float* eb1 = (const float*)d_in[8];
  const float* dWih0 = (const float*)d_in[9];
  const float* dWhh0 = (const float*)d_in[10];
  const float* db0 = (const float*)d_in[11];
  const float* dWih1 = (const float*)d_in[12];
  const float* dWhh1 = (const float*)d_in[13];
  const float* db1 = (const float*)d_in[14];
  const float* fcW = (const float*)d_in[15];
  const float* fcb = (const float*)d_in[16];

  char* w = (char*)d_ws;
  _Float16* h0buf = (_Float16*)w; w += 2 * BB * HD * 2;
  _Float16* h1buf = (_Float16*)w; w += 2 * BB * HD * 2;
  float* c0buf = (float*)w; w += BB * HD * 4;
  float* c1buf = (float*)w; w += BB * HD * 4;
  float* predpart = (float*)w; w += 2 * 16 * BB * 4;
  int* flagsE = (int*)w; w += (NWG + 1) * 4;
  int* flagsD = (int*)w; w += (NWG + 1) * 4;

  init_kernel<<<dim3(128), dim3(256), 0, stream>>>(h0buf, h1buf, predpart, flagsE, flagsD);

  KP pe;
  pe.seq = prev; pe.mask = mask;
  pe.Wih0 = eWih0; pe.Whh0 = eWhh0; pe.b0 = eb0;
  pe.Wih1 = eWih1; pe.Whh1 = eWhh1; pe.b1 = eb1;
  pe.fcW = fcW; pe.fcb = fcb;
  pe.h0buf = h0buf; pe.h1buf = h1buf;
  pe.c0buf = c0buf; pe.c1buf = c1buf;
  pe.predpart = predpart; pe.flags = flagsE;
  pe.out = (float*)d_out;
  seq_kernel<0><<<dim3(NWG), dim3(NTHR), 0, stream>>>(pe);

  KP pd = pe;
  pd.seq = nxt;
  pd.Wih0 = dWih0; pd.Whh0 = dWhh0; pd.b0 = db0;
  pd.Wih1 = dWih1; pd.Whh1 = dWhh1; pd.b1 = db1;
  pd.flags = flagsD;
  seq_kernel<1><<<dim3(NWG), dim3(NTHR), 0, stream>>>(pd);
}